// Round 17
// baseline (339.008 us; speedup 1.0000x reference)
//
#include <hip/hip_runtime.h>
#include <float.h>
#include <math.h>

// ---------------------------------------------------------------------------
// EdgeGuidedCrossAttention, round 17.
// R17: proj3both redesigned: NO LDS, NO barriers. Each wave = 32 rows x 64
// cols (cg in {0,1}); W-frags streamed from global per-ks (hot 96KB set in
// L2), A-frags register-resident across the 3 matrices. Waves independent ->
// pure TLP latency hiding; LDS read volume (was ~1.2GB) -> 0.
// gemm_ln_both back to R15 shape (LN needs full-row waves).
// CSR atomic-free; K/V fp8; upd bf16 k-permuted.
// Node table (512 B/row): Q bf16 [0,256) | K fp8 [256,384) | V fp8 [384,512).
// ---------------------------------------------------------------------------

typedef __bf16 bf16x8 __attribute__((ext_vector_type(8)));
typedef __bf16 bf16x4 __attribute__((ext_vector_type(4)));
typedef float  f32x4  __attribute__((ext_vector_type(4)));
typedef float  f32x2  __attribute__((ext_vector_type(2)));
typedef unsigned int u32x2 __attribute__((ext_vector_type(2)));

__device__ __forceinline__ bf16x8 cvt8(const float* p) {
    f32x4 lo = *reinterpret_cast<const f32x4*>(p);
    f32x4 hi = *reinterpret_cast<const f32x4*>(p + 4);
    bf16x8 r;
    r[0] = (__bf16)lo[0]; r[1] = (__bf16)lo[1]; r[2] = (__bf16)lo[2]; r[3] = (__bf16)lo[3];
    r[4] = (__bf16)hi[0]; r[5] = (__bf16)hi[1]; r[6] = (__bf16)hi[2]; r[7] = (__bf16)hi[3];
    return r;
}

__device__ __forceinline__ unsigned pack_fp8x4(const float* v) {
    int w = __builtin_amdgcn_cvt_pk_fp8_f32(v[0], v[1], 0, false);
    w = __builtin_amdgcn_cvt_pk_fp8_f32(v[2], v[3], w, true);
    return (unsigned)w;
}

__device__ __forceinline__ void unpack_fp8x8(u32x2 p, float* out) {
    f32x2 t0 = __builtin_amdgcn_cvt_pk_f32_fp8((int)p[0], false);
    f32x2 t1 = __builtin_amdgcn_cvt_pk_f32_fp8((int)p[0], true);
    f32x2 t2 = __builtin_amdgcn_cvt_pk_f32_fp8((int)p[1], false);
    f32x2 t3 = __builtin_amdgcn_cvt_pk_f32_fp8((int)p[1], true);
    out[0] = t0[0]; out[1] = t0[1]; out[2] = t1[0]; out[3] = t1[1];
    out[4] = t2[0]; out[5] = t2[1]; out[6] = t3[0]; out[7] = t3[1];
}

// Stage one [128][128] bf16 matrix into LDS (512 threads, 4 x bf16x8 each),
// byte ^= ((row&7)<<4) swizzle. (Used by gemm_ln_both only.)
__device__ __forceinline__ void stage_w512(const __bf16* __restrict__ Ws, char* wlds, int tid) {
#pragma unroll
    for (int it = 0; it < 4; ++it) {
        int idx = it * 4096 + tid * 8;
        int byteoff = idx * 2;
        int row = byteoff >> 8;
        *reinterpret_cast<bf16x8*>(wlds + (byteoff ^ ((row & 7) << 4)))
            = *reinterpret_cast<const bf16x8*>(Ws + idx);
    }
}
__device__ __forceinline__ bf16x8 read_w(const char* wlds, int l15, int lg, int ni, int ks) {
    int row = ni * 16 + l15;
    int off = (row * 256 + ks * 64 + lg * 16) ^ ((row & 7) << 4);
    return *reinterpret_cast<const bf16x8*>(wlds + off);
}

// 8 [128,128] f32 -> bf16. Matrices 3,7 (Wo_pro, Wo_lig) get their k (col)
// dim permuted: pos = (c&15)*8 + (c>>4), matching the QKV/upd storage order.
__global__ __launch_bounds__(256) void cvt_weights(
    const float* w0, const float* w1, const float* w2, const float* w3,
    const float* w4, const float* w5, const float* w6, const float* w7,
    __bf16* __restrict__ dst)
{
    const float* srcs[8] = {w0, w1, w2, w3, w4, w5, w6, w7};
    int t = blockIdx.x * 256 + threadIdx.x;
    int mat = t >> 11;
    int base = (t & 2047) * 8;
    const float* s = srcs[mat];
    bool perm = (mat == 3) || (mat == 7);
    __bf16* d = dst + (size_t)mat * 16384;
#pragma unroll
    for (int u = 0; u < 8; ++u) {
        int idx = base + u;
        int row = idx >> 7, c = idx & 127;
        int pos = perm ? ((c & 15) * 8 + (c >> 4)) : c;
        d[row * 128 + pos] = (__bf16)s[idx];
    }
}

// bias[e] = ea[e,:].We; counting atomics ALSO return per-edge ranks, stored
// packed (rank0 | rank1<<16) for the atomic-free fill pass.
__global__ __launch_bounds__(256) void bias_count(
    const float* __restrict__ ea, const float* __restrict__ We,
    const int* __restrict__ pi, const int* __restrict__ li,
    float* __restrict__ bias, int* __restrict__ counts,
    unsigned* __restrict__ ranks, int Np, int E, int CE)
{
    int e = blockIdx.x * 256 + threadIdx.x;
    if (e >= E) return;
    const float2* row = reinterpret_cast<const float2*>(ea + (size_t)e * CE);
    float acc = 0.f;
    int h = CE >> 1;
    for (int c = 0; c < h; ++c) {
        float2 v = row[c];
        acc += v.x * We[2 * c] + v.y * We[2 * c + 1];
    }
    if (CE & 1) acc += ea[(size_t)e * CE + CE - 1] * We[CE - 1];
    bias[e] = acc;
    int r0 = atomicAdd(&counts[pi[e]], 1);
    int r1 = atomicAdd(&counts[Np + li[e]], 1);
    ranks[e] = (unsigned)(r0 & 0xFFFF) | ((unsigned)r1 << 16);
}

__global__ __launch_bounds__(256) void scan1(
    const int* __restrict__ counts, int* __restrict__ offs,
    int* __restrict__ bsums, int N)
{
    int idx = blockIdx.x * 256 + threadIdx.x;
    int v = (idx < N) ? counts[idx] : 0;
    int lane = threadIdx.x & 63, w = threadIdx.x >> 6;
    int x = v;
#pragma unroll
    for (int d = 1; d < 64; d <<= 1) {
        int y = __shfl_up(x, d);
        if (lane >= d) x += y;
    }
    __shared__ int wsum[4];
    if (lane == 63) wsum[w] = x;
    __syncthreads();
    int add = 0;
    for (int i = 0; i < w; ++i) add += wsum[i];
    x += add;
    if (idx < N) offs[idx] = x - v;
    if (threadIdx.x == 255) bsums[blockIdx.x] = x;
}

// single-block inclusive scan of block sums (nb <= 1024; nb=782 here)
__global__ __launch_bounds__(1024) void scan2(int* __restrict__ bsums, int nb)
{
    __shared__ int tmp[1024];
    int t = threadIdx.x;
    tmp[t] = (t < nb) ? bsums[t] : 0;
    __syncthreads();
    for (int d = 1; d < 1024; d <<= 1) {
        int y = (t >= d) ? tmp[t - d] : 0;
        __syncthreads();
        tmp[t] += y;
        __syncthreads();
    }
    if (t < nb) bsums[t] = tmp[t];
}

__global__ __launch_bounds__(256) void scan3(
    int* __restrict__ offs, const int* __restrict__ bsums, int N, int total)
{
    int idx = blockIdx.x * 256 + threadIdx.x;
    if (idx < N && blockIdx.x > 0) offs[idx] += bsums[blockIdx.x - 1];
    if (idx == 0) offs[N] = total;
}

// Atomic-free fill: position = offs[seg] + precomputed rank. 4B records
// {other:24b | bias fp8:8b}.
__global__ __launch_bounds__(256) void fill2(
    const int* __restrict__ pi, const int* __restrict__ li,
    const float* __restrict__ bias, const unsigned* __restrict__ ranks,
    const int* __restrict__ offs, unsigned* __restrict__ elist, int Np, int E)
{
    int e = blockIdx.x * 256 + threadIdx.x;
    if (e >= E) return;
    int p = pi[e], l = li[e];
    unsigned rk = ranks[e];
    int w = __builtin_amdgcn_cvt_pk_fp8_f32(bias[e], 0.f, 0, false);
    unsigned b8 = (unsigned)w & 0xFFu;
    elist[offs[p] + (rk & 0xFFFFu)]      = ((unsigned)l << 8) | b8;
    elist[offs[Np + l] + (rk >> 16)]     = ((unsigned)p << 8) | b8;
}

// Fused QKV projection, both node sets. NO LDS, NO barriers.
// Wave = 32 rows x 64 cols (colgroup cg in {0,1}); W-frags streamed from
// global per-ks (L2-hot 96KB set); A-frags held in regs across 3 matrices.
__global__ __launch_bounds__(512) void proj3both(
    const float* __restrict__ Xp, const float* __restrict__ Xl,
    const __bf16* __restrict__ W16,
    const float* __restrict__ bq_p, const float* __restrict__ bk_p, const float* __restrict__ bv_p,
    const float* __restrict__ bq_l, const float* __restrict__ bk_l, const float* __restrict__ bv_l,
    char* __restrict__ QKVp, char* __restrict__ QKVl,
    int Np, int Nl, int nwp, int nwtot)
{
    int gw = blockIdx.x * 8 + (threadIdx.x >> 6);
    if (gw >= nwtot) return;
    int lane = threadIdx.x & 63;
    int l15 = lane & 15, lg = (lane >> 4) & 3;

    const float* A; const __bf16* Wms[3];
    const float* bsels[3]; char* QKV; int M, rowbase, cg;
    if (gw < nwp) {
        A = Xp; M = Np; rowbase = (gw >> 1) * 32; cg = gw & 1;
        Wms[0] = W16 + 0 * 16384; Wms[1] = W16 + 5 * 16384; Wms[2] = W16 + 6 * 16384;
        bsels[0] = bq_p; bsels[1] = bk_p; bsels[2] = bv_p; QKV = QKVp;
    } else {
        int g = gw - nwp;
        A = Xl; M = Nl; rowbase = (g >> 1) * 32; cg = g & 1;
        Wms[0] = W16 + 4 * 16384; Wms[1] = W16 + 1 * 16384; Wms[2] = W16 + 2 * 16384;
        bsels[0] = bq_l; bsels[1] = bk_l; bsels[2] = bv_l; QKV = QKVl;
    }
    if (rowbase >= M) return;

    int r0 = rowbase + l15;      if (r0 > M - 1) r0 = M - 1;
    int r1 = rowbase + 16 + l15; if (r1 > M - 1) r1 = M - 1;
    const float* Arow0 = A + (size_t)r0 * 128 + lg * 8;
    const float* Arow1 = A + (size_t)r1 * 128 + lg * 8;

    // A-frags held across all 3 matrices (32 VGPR).
    bf16x8 a0[4], a1[4];
#pragma unroll
    for (int ks = 0; ks < 4; ++ks) {
        a0[ks] = cvt8(Arow0 + ks * 32);
        a1[ks] = cvt8(Arow1 + ks * 32);
    }

#pragma unroll
    for (int mat = 0; mat < 3; ++mat) {
        const __bf16* Wsel = Wms[mat];
        // W base for this wave's cols: output row (col) = (cg*4+ni)*16 + l15
        const __bf16* Wb = Wsel + ((size_t)(cg * 4) * 16 + l15) * 128 + lg * 8;

        f32x4 acc0[4] = {}, acc1[4] = {};
#pragma unroll
        for (int ks = 0; ks < 4; ++ks) {
            bf16x8 w0 = *reinterpret_cast<const bf16x8*>(Wb + 0 * 2048 + ks * 32);
            bf16x8 w1 = *reinterpret_cast<const bf16x8*>(Wb + 1 * 2048 + ks * 32);
            bf16x8 w2 = *reinterpret_cast<const bf16x8*>(Wb + 2 * 2048 + ks * 32);
            bf16x8 w3 = *reinterpret_cast<const bf16x8*>(Wb + 3 * 2048 + ks * 32);
            acc0[0] = __builtin_amdgcn_mfma_f32_16x16x32_bf16(a0[ks], w0, acc0[0], 0, 0, 0);
            acc1[0] = __builtin_amdgcn_mfma_f32_16x16x32_bf16(a1[ks], w0, acc1[0], 0, 0, 0);
            acc0[1] = __builtin_amdgcn_mfma_f32_16x16x32_bf16(a0[ks], w1, acc0[1], 0, 0, 0);
            acc1[1] = __builtin_amdgcn_mfma_f32_16x16x32_bf16(a1[ks], w1, acc1[1], 0, 0, 0);
            acc0[2] = __builtin_amdgcn_mfma_f32_16x16x32_bf16(a0[ks], w2, acc0[2], 0, 0, 0);
            acc1[2] = __builtin_amdgcn_mfma_f32_16x16x32_bf16(a1[ks], w2, acc1[2], 0, 0, 0);
            acc0[3] = __builtin_amdgcn_mfma_f32_16x16x32_bf16(a0[ks], w3, acc0[3], 0, 0, 0);
            acc1[3] = __builtin_amdgcn_mfma_f32_16x16x32_bf16(a1[ks], w3, acc1[3], 0, 0, 0);
        }

        float bc[4];
#pragma unroll
        for (int ni = 0; ni < 4; ++ni) bc[ni] = bsels[mat][(cg * 4 + ni) * 16 + l15];

#pragma unroll
        for (int mi = 0; mi < 2; ++mi) {
#pragma unroll
            for (int r = 0; r < 4; ++r) {
                int row = rowbase + mi * 16 + lg * 4 + r;
                if (row < M) {
                    float v[4];
#pragma unroll
                    for (int ni = 0; ni < 4; ++ni)
                        v[ni] = (mi == 0 ? acc0[ni][r] : acc1[ni][r]) + bc[ni];
                    char* rowb = QKV + (size_t)row * 512;
                    if (mat == 0) {
                        bf16x4 o;   // cols (cg*4+ni)*16+l15 -> pos l15*8+cg*4+ni
#pragma unroll
                        for (int ni = 0; ni < 4; ++ni) o[ni] = (__bf16)v[ni];
                        *reinterpret_cast<bf16x4*>(rowb + l15 * 16 + cg * 8) = o;
                    } else {
                        *reinterpret_cast<unsigned*>(rowb + 256 + (mat - 1) * 128 + l15 * 8 + cg * 4)
                            = pack_fp8x4(v);
                    }
                }
            }
        }
    }
}

// One 16-lane group per target node (4 nodes/wave). Lane holds 8 (permuted)
// dims. K,V gathered as fp8; 4B edge records. No max-tracking; clamp at 60.
__global__ __launch_bounds__(256) void attend(
    const char* __restrict__ QKVp, const char* __restrict__ QKVl,
    const unsigned* __restrict__ elist, const int* __restrict__ offs,
    __bf16* __restrict__ upd_pro, __bf16* __restrict__ upd_lig,
    int Np, int Ntot, float scale)
{
    int node = blockIdx.x * 16 + (threadIdx.x >> 4);
    if (node >= Ntot) return;
    int l = threadIdx.x & 15;
    const char* Qrow; const char* KV; __bf16* upd;
    if (node < Np) {
        Qrow = QKVp + (size_t)node * 512; KV = QKVl;
        upd = upd_pro + (size_t)node * 128;
    } else {
        int n = node - Np;
        Qrow = QKVl + (size_t)n * 512; KV = QKVp;
        upd = upd_lig + (size_t)n * 128;
    }
    bf16x8 qv = *reinterpret_cast<const bf16x8*>(Qrow + l * 16);
    float q[8];
#pragma unroll
    for (int j = 0; j < 8; ++j) q[j] = (float)qv[j];

    int beg = offs[node], end = offs[node + 1];
    float d = 0.f;
    float acc[8] = {};
    for (int i = beg; i < end; ++i) {
        unsigned rec = elist[i];                  // group-uniform broadcast
        const char* row = KV + (size_t)(rec >> 8) * 512;
        f32x2 bt = __builtin_amdgcn_cvt_pk_f32_fp8((int)(rec & 0xFFu), false);
        u32x2 kk = *reinterpret_cast<const u32x2*>(row + 256 + l * 8);
        u32x2 vp = *reinterpret_cast<const u32x2*>(row + 384 + l * 8);
        float kf[8], vf[8];
        unpack_fp8x8(kk, kf);
        unpack_fp8x8(vp, vf);
        float dot = 0.f;
#pragma unroll
        for (int j = 0; j < 8; ++j) dot += q[j] * kf[j];
#pragma unroll
        for (int t = 1; t < 16; t <<= 1) dot += __shfl_xor(dot, t, 16);
        float s = fminf(dot * scale + bt[0], 60.f);
        float p = __expf(s);
        d += p;
#pragma unroll
        for (int j = 0; j < 8; ++j) acc[j] += p * vf[j];
    }
    float inv = 1.f / (d + 1e-8f);
    bf16x8 o;
#pragma unroll
    for (int j = 0; j < 8; ++j) o[j] = (__bf16)(acc[j] * inv);
    *reinterpret_cast<bf16x8*>(upd + l * 8) = o;   // permuted bf16 layout
}

// C = LayerNorm(X + A @ Wo^T + b), both node sets. Block = 512 thr, 16/wave
// (R15 shape). A (upd) bf16 k-permuted; Wo16's k-dim identically permuted.
__global__ __launch_bounds__(512) void gemm_ln_both(
    const __bf16* __restrict__ upd_pro, const __bf16* __restrict__ upd_lig,
    const float* __restrict__ Xp, const float* __restrict__ Xl,
    const __bf16* __restrict__ W16,
    const float* __restrict__ bo_p, const float* __restrict__ g_p, const float* __restrict__ be_p,
    const float* __restrict__ bo_l, const float* __restrict__ g_l, const float* __restrict__ be_l,
    float* __restrict__ out_pro, float* __restrict__ out_lig,
    int Np, int Nl, int nbp)
{
    __shared__ char wlds[32768];
    int bid = blockIdx.x;
    int tid = threadIdx.x;
    int lane = tid & 63, wv = tid >> 6;
    int l15 = lane & 15, lg = (lane >> 4) & 3;

    const __bf16* A; const float* X; const __bf16* Wo;
    const float *b, *g, *be_; float* C; int M, wrow;
    if (bid < nbp) {
        A = upd_pro; X = Xp; Wo = W16 + 3 * 16384;
        b = bo_p; g = g_p; be_ = be_p; C = out_pro; M = Np; wrow = bid * 128 + wv * 16;
    } else {
        A = upd_lig; X = Xl; Wo = W16 + 7 * 16384;
        b = bo_l; g = g_l; be_ = be_l; C = out_lig; M = Nl; wrow = (bid - nbp) * 128 + wv * 16;
    }
    stage_w512(Wo, wlds, tid);

    int r0 = wrow + l15; if (r0 > M - 1) r0 = M - 1;
    const __bf16* Arow0 = A + (size_t)r0 * 128 + lg * 8;
    bf16x8 a0[4];
#pragma unroll
    for (int ks = 0; ks < 4; ++ks)
        a0[ks] = *reinterpret_cast<const bf16x8*>(Arow0 + ks * 32);
    __syncthreads();

    f32x4 acc[8] = {};
#pragma unroll
    for (int ks = 0; ks < 4; ++ks) {
#pragma unroll
        for (int ni = 0; ni < 8; ++ni)
            acc[ni] = __builtin_amdgcn_mfma_f32_16x16x32_bf16(
                a0[ks], read_w(wlds, l15, lg, ni, ks), acc[ni], 0, 0, 0);
    }

    float bcol[8], gcol[8], becol[8];
#pragma unroll
    for (int ni = 0; ni < 8; ++ni) {
        bcol[ni]  = b[ni * 16 + l15];
        gcol[ni]  = g[ni * 16 + l15];
        becol[ni] = be_[ni * 16 + l15];
    }

#pragma unroll
    for (int r = 0; r < 4; ++r) {
        int row = wrow + lg * 4 + r;
        bool ok = row < M;
        int rowc = ok ? row : M - 1;
        float v[8];
#pragma unroll
        for (int ni = 0; ni < 8; ++ni) v[ni] = acc[ni][r] + bcol[ni];
        const float* Xr = X + (size_t)rowc * 128 + l15;
        float s1 = 0.f, s2 = 0.f;
#pragma unroll
        for (int ni = 0; ni < 8; ++ni) {
            v[ni] += Xr[ni * 16];
            s1 += v[ni]; s2 += v[ni] * v[ni];
        }
#pragma unroll
        for (int d = 1; d < 16; d <<= 1) {
            s1 += __shfl_xor(s1, d);
            s2 += __shfl_xor(s2, d);
        }
        float mu = s1 * 0.0078125f;
        float var = s2 * 0.0078125f - mu * mu;
        float rstd = rsqrtf(var + 1e-5f);
        if (ok) {
            float* Cr = C + (size_t)row * 128 + l15;
#pragma unroll
            for (int ni = 0; ni < 8; ++ni)
                Cr[ni * 16] = (v[ni] - mu) * rstd * gcol[ni] + becol[ni];
        }
    }
}

static inline int cdiv(int a, int b) { return (a + b - 1) / b; }

extern "C" void kernel_launch(void* const* d_in, const int* in_sizes, int n_in,
                              void* d_out, int out_size, void* d_ws, size_t ws_size,
                              hipStream_t stream)
{
    const float* pro_x  = (const float*)d_in[0];
    const float* lig_x  = (const float*)d_in[1];
    const int*   ei     = (const int*)d_in[2];
    const float* ea     = (const float*)d_in[3];
    const float* Wq_pro = (const float*)d_in[4];  const float* bq_pro = (const float*)d_in[5];
    const float* Wk_lig = (const float*)d_in[6];  const float* bk_lig = (const float*)d_in[7];
    const float* Wv_lig = (const float*)d_in[8];  const float* bv_lig = (const float*)d_in[9];
    const float* Wq_lig = (const float*)d_in[10]; const float* bq_lig = (const float*)d_in[11];
    const float* Wk_pro = (const float*)d_in[12]; const float* bk_pro = (const float*)d_in[13];
    const float* Wv_pro = (const float*)d_in[14]; const float* bv_pro = (const float*)d_in[15];
    const float* We     = (const float*)d_in[16];
    const float* Wo_pro = (const float*)d_in[17]; const float* bo_pro = (const float*)d_in[18];
    const float* Wo_lig = (const float*)d_in[19]; const float* bo_lig = (const float*)d_in[20];
    const float* g_pro  = (const float*)d_in[21]; const float* be_pro = (const float*)d_in[22];
    const float* g_lig  = (const float*)d_in[23]; const float* be_lig = (const float*)d_in[24];

    const int Np = in_sizes[0] / 128;
    const int Nl = in_sizes[1] / 128;
    const int E  = in_sizes[2] / 2;
    const int CE = in_sizes[3] / E;
    const int Nmax = Np > Nl ? Np : Nl;
    const int Ntot = Np + Nl;
    const int* pi = ei;
    const int* li = ei + E;

    float* out_pro = (float*)d_out;
    float* out_lig = out_pro + (size_t)Np * 128;

    float* ws = (float*)d_ws;
    size_t o = 0;
    char* QKVp = (char*)(ws + o); o += (size_t)Nmax * 128;       // [N][512B]
    char* QKVl = (char*)(ws + o); o += (size_t)Nmax * 128;
    float* bias = ws + o;   o += (size_t)E;
    unsigned* ranks = (unsigned*)(ws + o); o += (size_t)E;
    unsigned* elist = (unsigned*)(ws + o); o += 2 * (size_t)E;   // 2E x 4B
    int* counts = (int*)(ws + o); o += (size_t)Ntot + 8;
    int* offs   = (int*)(ws + o); o += (size_t)Ntot + 8;
    int* bsums  = (int*)(ws + o); o += 4096;
    __bf16* W16 = (__bf16*)(ws + o); o += 8 * 16384 / 2;         // [8][128][128] bf16
    __bf16* upd = (__bf16*)(ws + o); o += (size_t)Ntot * 64;     // permuted bf16
    __bf16* upd_pro = upd;
    __bf16* upd_lig = upd + (size_t)Np * 128;
    (void)ws_size; (void)n_in; (void)out_size;

    const float scale = 1.0f / sqrtf(128.0f);
    const int nEB = cdiv(E, 256);

    (void)hipMemsetAsync(counts, 0, (size_t)(Ntot + 1) * sizeof(int), stream);
    // W16 order: 0=Wq_pro 1=Wk_lig 2=Wv_lig 3=Wo_pro 4=Wq_lig 5=Wk_pro 6=Wv_pro 7=Wo_lig
    cvt_weights<<<64, 256, 0, stream>>>(Wq_pro, Wk_lig, Wv_lig, Wo_pro,
                                        Wq_lig, Wk_pro, Wv_pro, Wo_lig, W16);
    bias_count<<<nEB, 256, 0, stream>>>(ea, We, pi, li, bias, counts, ranks, Np, E, CE);

    const int nb1 = cdiv(Ntot, 256);   // 782 for 200k (<1024: scan2 ok)
    scan1<<<nb1, 256, 0, stream>>>(counts, offs, bsums, Ntot);
    scan2<<<1, 1024, 0, stream>>>(bsums, nb1);
    scan3<<<nb1, 256, 0, stream>>>(offs, bsums, Ntot, 2 * E);
    fill2<<<nEB, 256, 0, stream>>>(pi, li, bias, ranks, offs, elist, Np, E);

    const int nwp = cdiv(Np, 32) * 2, nwl = cdiv(Nl, 32) * 2;
    const int nwtot = nwp + nwl;
    proj3both<<<cdiv(nwtot, 8), 512, 0, stream>>>(pro_x, lig_x, W16,
        bq_pro, bk_pro, bv_pro, bq_lig, bk_lig, bv_lig,
        QKVp, QKVl, Np, Nl, nwp, nwtot);

    attend<<<cdiv(Ntot, 16), 256, 0, stream>>>(QKVp, QKVl, elist, offs,
        upd_pro, upd_lig, Np, Ntot, scale);

    const int nbp = cdiv(Np, 128), nbl = cdiv(Nl, 128);
    gemm_ln_both<<<nbp + nbl, 512, 0, stream>>>(upd_pro, upd_lig,
        pro_x, lig_x, W16, bo_pro, g_pro, be_pro, bo_lig, g_lig, be_lig,
        out_pro, out_lig, Np, Nl, nbp);
}

// Round 18
// 249.266 us; speedup vs baseline: 1.3600x; 1.3600x over previous
//
#include <hip/hip_runtime.h>
#include <float.h>
#include <math.h>

// ---------------------------------------------------------------------------
// EdgeGuidedCrossAttention, round 18 = R14 (best, 265us) + safe deltas:
//   (a) attend: 2-way edge ILP unroll (two K/V gathers in flight),
//   (b) cvt_weights+bias_count fused into one launch (grid split),
//   (c) scan2 folded into scan3 (per-block prefix over bsums) -> 8 dispatches.
// proj3both / gemm_ln_both are R14's proven shapes (64-row blocks, 256 thr).
// CSR atomic-free via ranks; K/V fp8; upd bf16 k-permuted.
// Node table (512 B/row): Q bf16 [0,256) | K fp8 [256,384) | V fp8 [384,512).
// ---------------------------------------------------------------------------

typedef __bf16 bf16x8 __attribute__((ext_vector_type(8)));
typedef float  f32x4  __attribute__((ext_vector_type(4)));
typedef float  f32x2  __attribute__((ext_vector_type(2)));
typedef unsigned int u32x2 __attribute__((ext_vector_type(2)));

__device__ __forceinline__ bf16x8 cvt8(const float* p) {
    f32x4 lo = *reinterpret_cast<const f32x4*>(p);
    f32x4 hi = *reinterpret_cast<const f32x4*>(p + 4);
    bf16x8 r;
    r[0] = (__bf16)lo[0]; r[1] = (__bf16)lo[1]; r[2] = (__bf16)lo[2]; r[3] = (__bf16)lo[3];
    r[4] = (__bf16)hi[0]; r[5] = (__bf16)hi[1]; r[6] = (__bf16)hi[2]; r[7] = (__bf16)hi[3];
    return r;
}

__device__ __forceinline__ u32x2 pack_fp8x8(const float* v) {
    int w0 = __builtin_amdgcn_cvt_pk_fp8_f32(v[0], v[1], 0, false);
    w0 = __builtin_amdgcn_cvt_pk_fp8_f32(v[2], v[3], w0, true);
    int w1 = __builtin_amdgcn_cvt_pk_fp8_f32(v[4], v[5], 0, false);
    w1 = __builtin_amdgcn_cvt_pk_fp8_f32(v[6], v[7], w1, true);
    u32x2 r; r[0] = (unsigned)w0; r[1] = (unsigned)w1;
    return r;
}

__device__ __forceinline__ void unpack_fp8x8(u32x2 p, float* out) {
    f32x2 t0 = __builtin_amdgcn_cvt_pk_f32_fp8((int)p[0], false);
    f32x2 t1 = __builtin_amdgcn_cvt_pk_f32_fp8((int)p[0], true);
    f32x2 t2 = __builtin_amdgcn_cvt_pk_f32_fp8((int)p[1], false);
    f32x2 t3 = __builtin_amdgcn_cvt_pk_f32_fp8((int)p[1], true);
    out[0] = t0[0]; out[1] = t0[1]; out[2] = t1[0]; out[3] = t1[1];
    out[4] = t2[0]; out[5] = t2[1]; out[6] = t3[0]; out[7] = t3[1];
}

// Stage one [128][128] bf16 matrix into LDS with byte ^= ((row&7)<<4) swizzle.
__device__ __forceinline__ void stage_w(const __bf16* __restrict__ Ws, char* wlds, int tid) {
#pragma unroll
    for (int it = 0; it < 8; ++it) {
        int idx = it * 2048 + tid * 8;
        int byteoff = idx * 2;
        int row = byteoff >> 8;
        *reinterpret_cast<bf16x8*>(wlds + (byteoff ^ ((row & 7) << 4)))
            = *reinterpret_cast<const bf16x8*>(Ws + idx);
    }
}
__device__ __forceinline__ bf16x8 read_w(const char* wlds, int l15, int lg, int ni, int ks) {
    int row = ni * 16 + l15;
    int off = (row * 256 + ks * 64 + lg * 16) ^ ((row & 7) << 4);
    return *reinterpret_cast<const bf16x8*>(wlds + off);
}

// Fused: blocks [0,64) convert the 8 weight matrices (k-perm for mats 3,7);
// blocks [64,..) compute bias + segment counts + per-edge ranks.
__global__ __launch_bounds__(256) void cvt_bias_count(
    const float* w0, const float* w1, const float* w2, const float* w3,
    const float* w4, const float* w5, const float* w6, const float* w7,
    __bf16* __restrict__ dst,
    const float* __restrict__ ea, const float* __restrict__ We,
    const int* __restrict__ pi, const int* __restrict__ li,
    float* __restrict__ bias, int* __restrict__ counts,
    unsigned* __restrict__ ranks, int Np, int E, int CE)
{
    if (blockIdx.x < 64) {
        const float* srcs[8] = {w0, w1, w2, w3, w4, w5, w6, w7};
        int t = blockIdx.x * 256 + threadIdx.x;
        int mat = t >> 11;
        int base = (t & 2047) * 8;
        const float* s = srcs[mat];
        bool perm = (mat == 3) || (mat == 7);
        __bf16* d = dst + (size_t)mat * 16384;
#pragma unroll
        for (int u = 0; u < 8; ++u) {
            int idx = base + u;
            int row = idx >> 7, c = idx & 127;
            int pos = perm ? ((c & 15) * 8 + (c >> 4)) : c;
            d[row * 128 + pos] = (__bf16)s[idx];
        }
        return;
    }
    int e = (blockIdx.x - 64) * 256 + threadIdx.x;
    if (e >= E) return;
    const float2* row = reinterpret_cast<const float2*>(ea + (size_t)e * CE);
    float acc = 0.f;
    int h = CE >> 1;
    for (int c = 0; c < h; ++c) {
        float2 v = row[c];
        acc += v.x * We[2 * c] + v.y * We[2 * c + 1];
    }
    if (CE & 1) acc += ea[(size_t)e * CE + CE - 1] * We[CE - 1];
    bias[e] = acc;
    int r0 = atomicAdd(&counts[pi[e]], 1);
    int r1 = atomicAdd(&counts[Np + li[e]], 1);
    ranks[e] = (unsigned)(r0 & 0xFFFF) | ((unsigned)r1 << 16);
}

__global__ __launch_bounds__(256) void scan1(
    const int* __restrict__ counts, int* __restrict__ offs,
    int* __restrict__ bsums, int N)
{
    int idx = blockIdx.x * 256 + threadIdx.x;
    int v = (idx < N) ? counts[idx] : 0;
    int lane = threadIdx.x & 63, w = threadIdx.x >> 6;
    int x = v;
#pragma unroll
    for (int d = 1; d < 64; d <<= 1) {
        int y = __shfl_up(x, d);
        if (lane >= d) x += y;
    }
    __shared__ int wsum[4];
    if (lane == 63) wsum[w] = x;
    __syncthreads();
    int add = 0;
    for (int i = 0; i < w; ++i) add += wsum[i];
    x += add;
    if (idx < N) offs[idx] = x - v;
    if (threadIdx.x == 255) bsums[blockIdx.x] = x;
}

// scan3 with scan2 folded in: each block computes its prefix over raw bsums.
__global__ __launch_bounds__(256) void scan3(
    int* __restrict__ offs, const int* __restrict__ bsums, int N, int total)
{
    int b = blockIdx.x, t = threadIdx.x;
    int s = 0;
    for (int i = t; i < b; i += 256) s += bsums[i];
#pragma unroll
    for (int d = 1; d < 64; d <<= 1) s += __shfl_xor(s, d);
    __shared__ int ws_[4];
    if ((t & 63) == 0) ws_[t >> 6] = s;
    __syncthreads();
    int pre = ws_[0] + ws_[1] + ws_[2] + ws_[3];
    int idx = b * 256 + t;
    if (idx < N) offs[idx] += pre;
    if (idx == 0) offs[N] = total;
}

// Atomic-free fill: position = offs[seg] + precomputed rank. 4B records
// {other:24b | bias fp8:8b}.
__global__ __launch_bounds__(256) void fill2(
    const int* __restrict__ pi, const int* __restrict__ li,
    const float* __restrict__ bias, const unsigned* __restrict__ ranks,
    const int* __restrict__ offs, unsigned* __restrict__ elist, int Np, int E)
{
    int e = blockIdx.x * 256 + threadIdx.x;
    if (e >= E) return;
    int p = pi[e], l = li[e];
    unsigned rk = ranks[e];
    int w = __builtin_amdgcn_cvt_pk_fp8_f32(bias[e], 0.f, 0, false);
    unsigned b8 = (unsigned)w & 0xFFu;
    elist[offs[p] + (rk & 0xFFFFu)]  = ((unsigned)l << 8) | b8;
    elist[offs[Np + l] + (rk >> 16)] = ((unsigned)p << 8) | b8;
}

// Fused QKV projection (R14 shape). Block = 64 rows (4 waves x 16 rows);
// W staged in LDS per matrix; A-frags in registers across the 3 matrices.
__global__ __launch_bounds__(256) void proj3both(
    const float* __restrict__ Xp, const float* __restrict__ Xl,
    const __bf16* __restrict__ W16,
    const float* __restrict__ bq_p, const float* __restrict__ bk_p, const float* __restrict__ bv_p,
    const float* __restrict__ bq_l, const float* __restrict__ bk_l, const float* __restrict__ bv_l,
    char* __restrict__ QKVp, char* __restrict__ QKVl,
    int Np, int Nl, int nbp)
{
    __shared__ char wlds[32768];
    int bid = blockIdx.x;
    int tid = threadIdx.x;
    int lane = tid & 63, wv = tid >> 6;
    int l15 = lane & 15, lg = lane >> 4;

    const float* A; const __bf16* Wms[3];
    const float* bsels[3]; char* QKV; int M, wrow;
    if (bid < nbp) {
        A = Xp; M = Np; wrow = bid * 64 + wv * 16;
        Wms[0] = W16 + 0 * 16384; Wms[1] = W16 + 5 * 16384; Wms[2] = W16 + 6 * 16384;
        bsels[0] = bq_p; bsels[1] = bk_p; bsels[2] = bv_p; QKV = QKVp;
    } else {
        A = Xl; M = Nl; wrow = (bid - nbp) * 64 + wv * 16;
        Wms[0] = W16 + 4 * 16384; Wms[1] = W16 + 1 * 16384; Wms[2] = W16 + 2 * 16384;
        bsels[0] = bq_l; bsels[1] = bk_l; bsels[2] = bv_l; QKV = QKVl;
    }
    int r0 = wrow + l15; if (r0 > M - 1) r0 = M - 1;
    const float* Arow0 = A + (size_t)r0 * 128 + lg * 8;

    bf16x8 a0[4];                       // A-frags: loaded once (16 VGPR)
#pragma unroll
    for (int ks = 0; ks < 4; ++ks) a0[ks] = cvt8(Arow0 + ks * 32);

#pragma unroll
    for (int mat = 0; mat < 3; ++mat) {
        __syncthreads();                 // prev-mat LDS reads complete
        stage_w(Wms[mat], wlds, tid);
        __syncthreads();

        f32x4 acc[8] = {};
#pragma unroll
        for (int ks = 0; ks < 4; ++ks) {
#pragma unroll
            for (int ni = 0; ni < 8; ++ni)
                acc[ni] = __builtin_amdgcn_mfma_f32_16x16x32_bf16(
                    a0[ks], read_w(wlds, l15, lg, ni, ks), acc[ni], 0, 0, 0);
        }
        float bc[8];
#pragma unroll
        for (int ni = 0; ni < 8; ++ni) bc[ni] = bsels[mat][ni * 16 + l15];
#pragma unroll
        for (int r = 0; r < 4; ++r) {
            int row = wrow + lg * 4 + r;
            if (row < M) {
                float v[8];              // col 16*ni+l15 -> stored pos l15*8+ni
#pragma unroll
                for (int ni = 0; ni < 8; ++ni) v[ni] = acc[ni][r] + bc[ni];
                char* rowb = QKV + (size_t)row * 512;
                if (mat == 0) {
                    bf16x8 o;
#pragma unroll
                    for (int ni = 0; ni < 8; ++ni) o[ni] = (__bf16)v[ni];
                    *reinterpret_cast<bf16x8*>(rowb + l15 * 16) = o;
                } else {
                    *reinterpret_cast<u32x2*>(rowb + 256 + (mat - 1) * 128 + l15 * 8)
                        = pack_fp8x8(v);
                }
            }
        }
    }
}

// One 16-lane group per target node (4 nodes/wave); 2-way edge ILP unroll.
// Lane holds 8 (permuted) dims; K,V fp8; 4B edge records; clamp at 60.
__global__ __launch_bounds__(256) void attend(
    const char* __restrict__ QKVp, const char* __restrict__ QKVl,
    const unsigned* __restrict__ elist, const int* __restrict__ offs,
    __bf16* __restrict__ upd_pro, __bf16* __restrict__ upd_lig,
    int Np, int Ntot, float scale)
{
    int node = blockIdx.x * 16 + (threadIdx.x >> 4);
    if (node >= Ntot) return;
    int l = threadIdx.x & 15;
    const char* Qrow; const char* KV; __bf16* upd;
    if (node < Np) {
        Qrow = QKVp + (size_t)node * 512; KV = QKVl;
        upd = upd_pro + (size_t)node * 128;
    } else {
        int n = node - Np;
        Qrow = QKVl + (size_t)n * 512; KV = QKVp;
        upd = upd_lig + (size_t)n * 128;
    }
    bf16x8 qv = *reinterpret_cast<const bf16x8*>(Qrow + l * 16);
    float q[8];
#pragma unroll
    for (int j = 0; j < 8; ++j) q[j] = (float)qv[j];

    int beg = offs[node], end = offs[node + 1];
    float d = 0.f;
    float acc[8] = {};
    int i = beg;
    for (; i + 1 < end; i += 2) {
        unsigned rec0 = elist[i], rec1 = elist[i + 1];
        const char* row0 = KV + (size_t)(rec0 >> 8) * 512;
        const char* row1 = KV + (size_t)(rec1 >> 8) * 512;
        u32x2 kk0 = *reinterpret_cast<const u32x2*>(row0 + 256 + l * 8);
        u32x2 vp0 = *reinterpret_cast<const u32x2*>(row0 + 384 + l * 8);
        u32x2 kk1 = *reinterpret_cast<const u32x2*>(row1 + 256 + l * 8);
        u32x2 vp1 = *reinterpret_cast<const u32x2*>(row1 + 384 + l * 8);
        float kf0[8], vf0[8], kf1[8], vf1[8];
        unpack_fp8x8(kk0, kf0); unpack_fp8x8(vp0, vf0);
        unpack_fp8x8(kk1, kf1); unpack_fp8x8(vp1, vf1);
        float dot0 = 0.f, dot1 = 0.f;
#pragma unroll
        for (int j = 0; j < 8; ++j) { dot0 += q[j] * kf0[j]; dot1 += q[j] * kf1[j]; }
#pragma unroll
        for (int t = 1; t < 16; t <<= 1) {
            dot0 += __shfl_xor(dot0, t, 16);
            dot1 += __shfl_xor(dot1, t, 16);
        }
        f32x2 b0 = __builtin_amdgcn_cvt_pk_f32_fp8((int)(rec0 & 0xFFu), false);
        f32x2 b1 = __builtin_amdgcn_cvt_pk_f32_fp8((int)(rec1 & 0xFFu), false);
        float p0 = __expf(fminf(dot0 * scale + b0[0], 60.f));
        float p1 = __expf(fminf(dot1 * scale + b1[0], 60.f));
        d += p0 + p1;
#pragma unroll
        for (int j = 0; j < 8; ++j) acc[j] += p0 * vf0[j] + p1 * vf1[j];
    }
    if (i < end) {
        unsigned rec = elist[i];
        const char* row = KV + (size_t)(rec >> 8) * 512;
        u32x2 kk = *reinterpret_cast<const u32x2*>(row + 256 + l * 8);
        u32x2 vp = *reinterpret_cast<const u32x2*>(row + 384 + l * 8);
        float kf[8], vf[8];
        unpack_fp8x8(kk, kf); unpack_fp8x8(vp, vf);
        float dot = 0.f;
#pragma unroll
        for (int j = 0; j < 8; ++j) dot += q[j] * kf[j];
#pragma unroll
        for (int t = 1; t < 16; t <<= 1) dot += __shfl_xor(dot, t, 16);
        f32x2 bt = __builtin_amdgcn_cvt_pk_f32_fp8((int)(rec & 0xFFu), false);
        float p = __expf(fminf(dot * scale + bt[0], 60.f));
        d += p;
#pragma unroll
        for (int j = 0; j < 8; ++j) acc[j] += p * vf[j];
    }
    float inv = 1.f / (d + 1e-8f);
    bf16x8 o;
#pragma unroll
    for (int j = 0; j < 8; ++j) o[j] = (__bf16)(acc[j] * inv);
    *reinterpret_cast<bf16x8*>(upd + l * 8) = o;   // permuted bf16 layout
}

// C = LayerNorm(X + A @ Wo^T + b), both node sets (R14 shape: 64-row blocks).
// A (upd) bf16 with k-permuted cols; Wo16's k-dim identically permuted.
__global__ __launch_bounds__(256) void gemm_ln_both(
    const __bf16* __restrict__ upd_pro, const __bf16* __restrict__ upd_lig,
    const float* __restrict__ Xp, const float* __restrict__ Xl,
    const __bf16* __restrict__ W16,
    const float* __restrict__ bo_p, const float* __restrict__ g_p, const float* __restrict__ be_p,
    const float* __restrict__ bo_l, const float* __restrict__ g_l, const float* __restrict__ be_l,
    float* __restrict__ out_pro, float* __restrict__ out_lig,
    int Np, int Nl, int nbp)
{
    __shared__ char wlds[32768];
    int bid = blockIdx.x;
    int tid = threadIdx.x;
    int lane = tid & 63, wv = tid >> 6;
    int l15 = lane & 15, lg = lane >> 4;

    const __bf16* A; const float* X; const __bf16* Wo;
    const float *b, *g, *be_; float* C; int M, wrow;
    if (bid < nbp) {
        A = upd_pro; X = Xp; Wo = W16 + 3 * 16384;
        b = bo_p; g = g_p; be_ = be_p; C = out_pro; M = Np; wrow = bid * 64 + wv * 16;
    } else {
        A = upd_lig; X = Xl; Wo = W16 + 7 * 16384;
        b = bo_l; g = g_l; be_ = be_l; C = out_lig; M = Nl; wrow = (bid - nbp) * 64 + wv * 16;
    }
    stage_w(Wo, wlds, tid);

    int r0 = wrow + l15; if (r0 > M - 1) r0 = M - 1;
    const __bf16* Arow0 = A + (size_t)r0 * 128 + lg * 8;
    bf16x8 a0[4];
#pragma unroll
    for (int ks = 0; ks < 4; ++ks)
        a0[ks] = *reinterpret_cast<const bf16x8*>(Arow0 + ks * 32);
    __syncthreads();

    f32x4 acc[8] = {};
#pragma unroll
    for (int ks = 0; ks < 4; ++ks) {
#pragma unroll
        for (int ni = 0; ni < 8; ++ni)
            acc[ni] = __builtin_amdgcn_mfma_f32_16x16x32_bf16(
                a0[ks], read_w(wlds, l15, lg, ni, ks), acc[ni], 0, 0, 0);
    }

    float bcol[8], gcol[8], becol[8];
#pragma unroll
    for (int ni = 0; ni < 8; ++ni) {
        bcol[ni]  = b[ni * 16 + l15];
        gcol[ni]  = g[ni * 16 + l15];
        becol[ni] = be_[ni * 16 + l15];
    }

#pragma unroll
    for (int r = 0; r < 4; ++r) {
        int row = wrow + lg * 4 + r;
        bool ok = row < M;
        int rowc = ok ? row : M - 1;
        float v[8];
#pragma unroll
        for (int ni = 0; ni < 8; ++ni) v[ni] = acc[ni][r] + bcol[ni];
        const float* Xr = X + (size_t)rowc * 128 + l15;
        float s1 = 0.f, s2 = 0.f;
#pragma unroll
        for (int ni = 0; ni < 8; ++ni) {
            v[ni] += Xr[ni * 16];
            s1 += v[ni]; s2 += v[ni] * v[ni];
        }
#pragma unroll
        for (int d = 1; d < 16; d <<= 1) {
            s1 += __shfl_xor(s1, d);
            s2 += __shfl_xor(s2, d);
        }
        float mu = s1 * 0.0078125f;
        float var = s2 * 0.0078125f - mu * mu;
        float rstd = rsqrtf(var + 1e-5f);
        if (ok) {
            float* Cr = C + (size_t)row * 128 + l15;
#pragma unroll
            for (int ni = 0; ni < 8; ++ni)
                Cr[ni * 16] = (v[ni] - mu) * rstd * gcol[ni] + becol[ni];
        }
    }
}

static inline int cdiv(int a, int b) { return (a + b - 1) / b; }

extern "C" void kernel_launch(void* const* d_in, const int* in_sizes, int n_in,
                              void* d_out, int out_size, void* d_ws, size_t ws_size,
                              hipStream_t stream)
{
    const float* pro_x  = (const float*)d_in[0];
    const float* lig_x  = (const float*)d_in[1];
    const int*   ei     = (const int*)d_in[2];
    const float* ea     = (const float*)d_in[3];
    const float* Wq_pro = (const float*)d_in[4];  const float* bq_pro = (const float*)d_in[5];
    const float* Wk_lig = (const float*)d_in[6];  const float* bk_lig = (const float*)d_in[7];
    const float* Wv_lig = (const float*)d_in[8];  const float* bv_lig = (const float*)d_in[9];
    const float* Wq_lig = (const float*)d_in[10]; const float* bq_lig = (const float*)d_in[11];
    const float* Wk_pro = (const float*)d_in[12]; const float* bk_pro = (const float*)d_in[13];
    const float* Wv_pro = (const float*)d_in[14]; const float* bv_pro = (const float*)d_in[15];
    const float* We     = (const float*)d_in[16];
    const float* Wo_pro = (const float*)d_in[17]; const float* bo_pro = (const float*)d_in[18];
    const float* Wo_lig = (const float*)d_in[19]; const float* bo_lig = (const float*)d_in[20];
    const float* g_pro  = (const float*)d_in[21]; const float* be_pro = (const float*)d_in[22];
    const float* g_lig  = (const float*)d_in[23]; const float* be_lig = (const float*)d_in[24];

    const int Np = in_sizes[0] / 128;
    const int Nl = in_sizes[1] / 128;
    const int E  = in_sizes[2] / 2;
    const int CE = in_sizes[3] / E;
    const int Nmax = Np > Nl ? Np : Nl;
    const int Ntot = Np + Nl;
    const int* pi = ei;
    const int* li = ei + E;

    float* out_pro = (float*)d_out;
    float* out_lig = out_pro + (size_t)Np * 128;

    float* ws = (float*)d_ws;
    size_t o = 0;
    char* QKVp = (char*)(ws + o); o += (size_t)Nmax * 128;       // [N][512B]
    char* QKVl = (char*)(ws + o); o += (size_t)Nmax * 128;
    float* bias = ws + o;   o += (size_t)E;
    unsigned* ranks = (unsigned*)(ws + o); o += (size_t)E;
    unsigned* elist = (unsigned*)(ws + o); o += 2 * (size_t)E;   // 2E x 4B
    int* counts = (int*)(ws + o); o += (size_t)Ntot + 8;
    int* offs   = (int*)(ws + o); o += (size_t)Ntot + 8;
    int* bsums  = (int*)(ws + o); o += 4096;
    __bf16* W16 = (__bf16*)(ws + o); o += 8 * 16384 / 2;         // [8][128][128] bf16
    __bf16* upd = (__bf16*)(ws + o); o += (size_t)Ntot * 64;     // permuted bf16
    __bf16* upd_pro = upd;
    __bf16* upd_lig = upd + (size_t)Np * 128;
    (void)ws_size; (void)n_in; (void)out_size;

    const float scale = 1.0f / sqrtf(128.0f);
    const int nEB = cdiv(E, 256);

    (void)hipMemsetAsync(counts, 0, (size_t)(Ntot + 1) * sizeof(int), stream);
    // W16 order: 0=Wq_pro 1=Wk_lig 2=Wv_lig 3=Wo_pro 4=Wq_lig 5=Wk_pro 6=Wv_pro 7=Wo_lig
    cvt_bias_count<<<64 + nEB, 256, 0, stream>>>(
        Wq_pro, Wk_lig, Wv_lig, Wo_pro, Wq_lig, Wk_pro, Wv_pro, Wo_lig, W16,
        ea, We, pi, li, bias, counts, ranks, Np, E, CE);

    const int nb1 = cdiv(Ntot, 256);
    scan1<<<nb1, 256, 0, stream>>>(counts, offs, bsums, Ntot);
    scan3<<<nb1, 256, 0, stream>>>(offs, bsums, Ntot, 2 * E);
    fill2<<<nEB, 256, 0, stream>>>(pi, li, bias, ranks, offs, elist, Np, E);

    const int nbp = cdiv(Np, 64), nbl = cdiv(Nl, 64);
    proj3both<<<nbp + nbl, 256, 0, stream>>>(pro_x, lig_x, W16,
        bq_pro, bk_pro, bv_pro, bq_lig, bk_lig, bv_lig,
        QKVp, QKVl, Np, Nl, nbp);

    attend<<<cdiv(Ntot, 16), 256, 0, stream>>>(QKVp, QKVl, elist, offs,
        upd_pro, upd_lig, Np, Ntot, scale);

    gemm_ln_both<<<nbp + nbl, 256, 0, stream>>>(upd_pro, upd_lig,
        pro_x, lig_x, W16, bo_pro, g_pro, be_pro, bo_lig, g_lig, be_lig,
        out_pro, out_lig, Np, Nl, nbp);
}